// Round 12
// baseline (308.105 us; speedup 1.0000x reference)
//
#include <hip/hip_runtime.h>
#include <stdint.h>

#define NN 100000
#define NE 1000000
#define NTILES (NE / 64)
#define NB_SCAN 391  // ceil(NN/256)

typedef __attribute__((ext_vector_type(8))) short bf16x8;
typedef __attribute__((ext_vector_type(4))) float f32x4;

// ws layout (bytes)
static const size_t OFF_W1K   = 0;         // 128*32 bf16 (8 KB)
static const size_t OFF_WVK   = 8192;      // 128*32 bf16 (8 KB): Wv K-padded
static const size_t OFF_W1BP  = 16384;     // 128*128 bf16 (32 KB), slot-permuted
static const size_t OFF_MTB   = 49152;     // 128*128 bf16 (32 KB)
static const size_t OFF_RP    = 81920;     // (NN+1) int rowptr
static const size_t OFF_CUR   = 524288;    // NN int cursor; later aliased as inv_denom
static const size_t OFF_PART  = 1048576;   // NB_SCAN*256 int
static const size_t OFF_BSUM  = 1572864;   // NB_SCAN int
static const size_t OFF_BSUMX = 1576960;   // NB_SCAN int
static const size_t OFF_CNT   = 1581056;   // NN int histogram
static const size_t OFF_PT    = 2097152;   // NE int2 {edge, tgt} sorted (8 MB)
static const size_t OFF_EVALS = 10485760;  // NE f32 (sorted order, 4 MB)
static const size_t OFF_EAS   = 14485760;  // NE * 5 uint (bf16x10 packed, 20 MB)
static const size_t OFF_SNODE = 34485760;  // NN*128 bf16 (25.6 MB)

__device__ inline unsigned short f2bf(float f) {
    const unsigned int u = __float_as_uint(f);
    return (unsigned short)((u + 0x7fffu + ((u >> 16) & 1u)) >> 16);  // RNE
}

__device__ inline unsigned int cvtpk(float lo, float hi) {
    unsigned int r;
    asm("v_cvt_pk_bf16_f32 %0, %1, %2" : "=v"(r) : "v"(lo), "v"(hi));
    return r;
}

__device__ inline float lk(float v) {  // leaky_relu 0.01
    return fmaxf(v, 0.f) + 0.01f * fminf(v, 0.f);
}

union BU { bf16x8 v; uint4 u; };

// ---------------------------------------------------------------------------
// prep: w1k/wvk = bf16(Wk/Wv) K-padded to 32; w1bp = W1b slot-permuted bf16;
// mtb[i][l] = bf16((W1a@Wq)[i][l]).   (R9-exact)
// ---------------------------------------------------------------------------
__global__ __launch_bounds__(128) void prep_kernel(
    const float* __restrict__ W1, const float* __restrict__ Wq,
    const float* __restrict__ Wk, const float* __restrict__ Wv,
    unsigned short* __restrict__ w1k, unsigned short* __restrict__ wvk,
    unsigned short* __restrict__ w1bp, unsigned short* __restrict__ mtb)
{
    const int l = blockIdx.x;   // 0..127
    const int i = threadIdx.x;  // 0..127
    float acc = 0.f;
#pragma unroll 8
    for (int j = 0; j < 128; ++j)
        acc = fmaf(W1[i * 256 + j], Wq[j * 128 + l], acc);
    mtb[i * 128 + l] = f2bf(acc);
    if (i < 32) {
        w1k[l * 32 + i] = (i < 10) ? f2bf(Wk[l * 10 + i]) : (unsigned short)0;
        wvk[l * 32 + i] = (i < 10) ? f2bf(Wv[l * 10 + i]) : (unsigned short)0;
    }
    const int m = l;
    const int j = (m & ~31) + 16 * ((m >> 2) & 1) + 4 * ((m >> 3) & 3) + (m & 3);
    w1bp[i * 128 + m] = f2bf(W1[i * 256 + 128 + j]);
}

// ---------------------------------------------------------------------------
// node scores via MFMA: s_node[n][i] = bf16( x[n]@M^T + b1 ).  (R9-exact)
// ---------------------------------------------------------------------------
__global__ __launch_bounds__(256) void node_score_kernel(
    const float* __restrict__ x, const unsigned short* __restrict__ mtb_g,
    const float* __restrict__ b1, unsigned short* __restrict__ s_node)
{
    __shared__ __align__(16) unsigned short mt_s[128 * 136];
    const int t = threadIdx.x;
    for (int idx = t; idx < 2048; idx += 256) {
        const uint4 v = ((const uint4*)mtb_g)[idx];
        const int row = idx >> 4, q = idx & 15;
        *(uint4*)&mt_s[row * 136 + q * 8] = v;
    }
    __syncthreads();

    const int lane = t & 63;
    const int wave = t >> 6;
    const int h    = lane >> 4;
    const int e15  = lane & 15;
    const int node = blockIdx.x * 64 + wave * 16 + e15;
    const int nc   = min(node, NN - 1);
    const int lds_base = e15 * 136 + h * 8;

    const f32x4 z4 = {0.f, 0.f, 0.f, 0.f};
    f32x4 acc[8];
#pragma unroll
    for (int g = 0; g < 8; ++g) acc[g] = z4;

#pragma unroll
    for (int s = 0; s < 4; ++s) {
        const float4 xa = *(const float4*)&x[(size_t)nc * 128 + s * 32 + h * 8];
        const float4 xb = *(const float4*)&x[(size_t)nc * 128 + s * 32 + h * 8 + 4];
        BU bx;
        bx.u.x = cvtpk(xa.x, xa.y);
        bx.u.y = cvtpk(xa.z, xa.w);
        bx.u.z = cvtpk(xb.x, xb.y);
        bx.u.w = cvtpk(xb.z, xb.w);
#pragma unroll
        for (int g = 0; g < 8; ++g) {
            const bf16x8 a = *(const bf16x8*)&mt_s[lds_base + g * (16 * 136) + s * 32];
            acc[g] = __builtin_amdgcn_mfma_f32_16x16x32_bf16(a, bx.v, acc[g], 0, 0, 0);
        }
    }

    if (node < NN) {
#pragma unroll
        for (int g = 0; g < 8; ++g) {
            const float4 bb = *(const float4*)&b1[g * 16 + h * 4];
            uint2 o2;
            o2.x = cvtpk(acc[g][0] + bb.x, acc[g][1] + bb.y);
            o2.y = cvtpk(acc[g][2] + bb.z, acc[g][3] + bb.w);
            *(uint2*)&s_node[(size_t)node * 128 + g * 16 + h * 4] = o2;
        }
    }
}

// ---------------------------------------------------------------------------
// CSR build: histogram -> block scan -> fill {edge,tgt} pairs in sorted order
// ---------------------------------------------------------------------------
__global__ __launch_bounds__(256) void hist_kernel(
    const int* __restrict__ tgt, int* __restrict__ cnt)
{
    const int e = blockIdx.x * 256 + threadIdx.x;
    if (e < NE) atomicAdd(&cnt[tgt[e]], 1);
}

__global__ __launch_bounds__(256) void scan1_kernel(
    const int* __restrict__ cnt, int* __restrict__ part, int* __restrict__ bsum)
{
    __shared__ int s[256];
    const int t = threadIdx.x;
    const int idx = blockIdx.x * 256 + t;
    const int v = (idx < NN) ? cnt[idx] : 0;
    s[t] = v;
    __syncthreads();
    for (int off = 1; off < 256; off <<= 1) {
        const int u = (t >= off) ? s[t - off] : 0;
        __syncthreads();
        s[t] += u;
        __syncthreads();
    }
    part[idx] = s[t] - v;  // exclusive
    if (t == 255) bsum[blockIdx.x] = s[255];
}

__global__ __launch_bounds__(512) void scan2_kernel(
    const int* __restrict__ bsum, int* __restrict__ bsumx)
{
    __shared__ int s[512];
    const int t = threadIdx.x;
    const int v = (t < NB_SCAN) ? bsum[t] : 0;
    s[t] = v;
    __syncthreads();
    for (int off = 1; off < 512; off <<= 1) {
        const int u = (t >= off) ? s[t - off] : 0;
        __syncthreads();
        s[t] += u;
        __syncthreads();
    }
    if (t < NB_SCAN) bsumx[t] = s[t] - v;  // exclusive
}

__global__ __launch_bounds__(256) void scan3_kernel(
    const int* __restrict__ part, const int* __restrict__ bsumx,
    int* __restrict__ rowptr, int* __restrict__ cursor)
{
    const int idx = blockIdx.x * 256 + threadIdx.x;
    if (idx < NN) {
        const int rp = part[idx] + bsumx[idx >> 8];
        rowptr[idx] = rp;
        cursor[idx] = rp;
    }
    if (idx == 0) rowptr[NN] = NE;
}

__global__ __launch_bounds__(256) void fill_kernel(
    const int* __restrict__ tgt, int* __restrict__ cursor, int2* __restrict__ pt)
{
    const int e = blockIdx.x * 256 + threadIdx.x;
    if (e < NE) {
        const int tg = tgt[e];
        const int p  = atomicAdd(&cursor[tg], 1);
        pt[p] = make_int2(e, tg);
    }
}

// ---------------------------------------------------------------------------
// edge scores via MFMA, CSR-sorted, 2-deep software pipeline. R9 math/layout;
// R12: grid 1024 (exactly 4 blocks/CU) + unroll-2 tile loop (pipeline rotate
// movs removed by register renaming).
// ---------------------------------------------------------------------------
__global__ __launch_bounds__(256) void edge_kernel(
    const float* __restrict__ edge_attr, const int2* __restrict__ pt,
    const unsigned short* __restrict__ w1k_g, const unsigned short* __restrict__ w1bp_g,
    const float* __restrict__ W2, const float* __restrict__ b2,
    const unsigned short* __restrict__ s_node,
    float* __restrict__ e_vals, unsigned int* __restrict__ eas)
{
    __shared__ __align__(16) unsigned short w1b_s[128 * 136];

    const int t = threadIdx.x;
    for (int idx = t; idx < 2048; idx += 256) {
        const uint4 v = ((const uint4*)w1bp_g)[idx];
        const int row = idx >> 4, q = idx & 15;
        *(uint4*)&w1b_s[row * 136 + q * 8] = v;
    }

    const int lane = t & 63;
    const int wave = t >> 6;
    const int h    = lane >> 4;
    const int e15  = lane & 15;

    bf16x8 a1[8];
#pragma unroll
    for (int f = 0; f < 8; ++f)
        a1[f] = *(const bf16x8*)&w1k_g[(f * 16 + e15) * 32 + h * 8];
    const float b2v = b2[0];

    __syncthreads();

    const int lds_base = e15 * 136 + h * 8;
    const int cstep    = gridDim.x * 64;

    int c = blockIdx.x * 64 + wave * 16 + e15;  // sorted edge index

    int2 ptc = pt[min(c, NE - 1)];
    int2 ptn = pt[min(c + cstep, NE - 1)];

    uint2 sn[8];
#pragma unroll
    for (int g = 0; g < 8; ++g)
        sn[g] = *(const uint2*)&s_node[(size_t)ptc.y * 128 + g * 16 + h * 4];

    float ea0 = 0.f, ea1 = 0.f, ea2 = 0.f, ea3 = 0.f, ea4 = 0.f;
    float ea5 = 0.f, ea6 = 0.f, ea7 = 0.f, ea8 = 0.f, ea9 = 0.f;
    {
        const float* pa = edge_attr + (size_t)ptc.x * 10;
        if (h == 0) {
            const float2 u0 = *(const float2*)(pa + 0);
            const float2 u1 = *(const float2*)(pa + 2);
            const float2 u2 = *(const float2*)(pa + 4);
            const float2 u3 = *(const float2*)(pa + 6);
            ea0 = u0.x; ea1 = u0.y; ea2 = u1.x; ea3 = u1.y;
            ea4 = u2.x; ea5 = u2.y; ea6 = u3.x; ea7 = u3.y;
        } else if (h == 1) {
            const float2 u4 = *(const float2*)(pa + 8);
            ea8 = u4.x; ea9 = u4.y;
        }
    }

#pragma unroll 2
    for (int tile = blockIdx.x; tile < NTILES; tile += gridDim.x, c += cstep) {
        const int2 ptn2 = pt[min(c + 2 * cstep, NE - 1)];
        uint2 sn_n[8];
#pragma unroll
        for (int g = 0; g < 8; ++g)
            sn_n[g] = *(const uint2*)&s_node[(size_t)ptn.y * 128 + g * 16 + h * 4];
        float en0 = 0.f, en1 = 0.f, en2 = 0.f, en3 = 0.f, en4 = 0.f;
        float en5 = 0.f, en6 = 0.f, en7 = 0.f, en8 = 0.f, en9 = 0.f;
        {
            const float* pa = edge_attr + (size_t)ptn.x * 10;
            if (h == 0) {
                const float2 u0 = *(const float2*)(pa + 0);
                const float2 u1 = *(const float2*)(pa + 2);
                const float2 u2 = *(const float2*)(pa + 4);
                const float2 u3 = *(const float2*)(pa + 6);
                en0 = u0.x; en1 = u0.y; en2 = u1.x; en3 = u1.y;
                en4 = u2.x; en5 = u2.y; en6 = u3.x; en7 = u3.y;
            } else if (h == 1) {
                const float2 u4 = *(const float2*)(pa + 8);
                en8 = u4.x; en9 = u4.y;
            }
        }

        bf16x8 b1 = (bf16x8){0, 0, 0, 0, 0, 0, 0, 0};
        {
            unsigned int* po = eas + (size_t)c * 5;
            if (h == 0) {
                BU bu;
                bu.u.x = cvtpk(ea0, ea1);
                bu.u.y = cvtpk(ea2, ea3);
                bu.u.z = cvtpk(ea4, ea5);
                bu.u.w = cvtpk(ea6, ea7);
                b1 = bu.v;
                po[0] = bu.u.x; po[1] = bu.u.y; po[2] = bu.u.z; po[3] = bu.u.w;
            } else if (h == 1) {
                BU bu;
                bu.u.x = cvtpk(ea8, ea9);
                bu.u.y = 0; bu.u.z = 0; bu.u.w = 0;
                b1 = bu.v;
                po[4] = bu.u.x;
            }
        }

        const f32x4 z4 = {0.f, 0.f, 0.f, 0.f};
        f32x4 acc1[8];
#pragma unroll
        for (int f = 0; f < 8; ++f)
            acc1[f] = __builtin_amdgcn_mfma_f32_16x16x32_bf16(a1[f], b1, z4, 0, 0, 0);

        bf16x8 pb[4];
#pragma unroll
        for (int s = 0; s < 4; ++s) {
            BU bu;
            bu.u.x = cvtpk(lk(acc1[2 * s][0]), lk(acc1[2 * s][1]));
            bu.u.y = cvtpk(lk(acc1[2 * s][2]), lk(acc1[2 * s][3]));
            bu.u.z = cvtpk(lk(acc1[2 * s + 1][0]), lk(acc1[2 * s + 1][1]));
            bu.u.w = cvtpk(lk(acc1[2 * s + 1][2]), lk(acc1[2 * s + 1][3]));
            pb[s] = bu.v;
        }

        float p = 0.f;
#pragma unroll
        for (int g2 = 0; g2 < 4; ++g2) {
            const int gA = 2 * g2, gB = 2 * g2 + 1;
            f32x4 accA = z4, accB = z4;
#pragma unroll
            for (int s = 0; s < 4; ++s) {
                const bf16x8 a2A = *(const bf16x8*)&w1b_s[lds_base + gA * (16 * 136) + s * 32];
                const bf16x8 a2B = *(const bf16x8*)&w1b_s[lds_base + gB * (16 * 136) + s * 32];
                accA = __builtin_amdgcn_mfma_f32_16x16x32_bf16(a2A, pb[s], accA, 0, 0, 0);
                accB = __builtin_amdgcn_mfma_f32_16x16x32_bf16(a2B, pb[s], accB, 0, 0, 0);
            }
            const float4 w2A = *(const float4*)&W2[gA * 16 + h * 4];
            const float4 w2B = *(const float4*)&W2[gB * 16 + h * 4];
            const uint2 svA = sn[gA], svB = sn[gB];
            p = fmaf(fmaxf(accA[0] + __uint_as_float(svA.x << 16), 0.f), w2A.x, p);
            p = fmaf(fmaxf(accA[1] + __uint_as_float(svA.x & 0xffff0000u), 0.f), w2A.y, p);
            p = fmaf(fmaxf(accA[2] + __uint_as_float(svA.y << 16), 0.f), w2A.z, p);
            p = fmaf(fmaxf(accA[3] + __uint_as_float(svA.y & 0xffff0000u), 0.f), w2A.w, p);
            p = fmaf(fmaxf(accB[0] + __uint_as_float(svB.x << 16), 0.f), w2B.x, p);
            p = fmaf(fmaxf(accB[1] + __uint_as_float(svB.x & 0xffff0000u), 0.f), w2B.y, p);
            p = fmaf(fmaxf(accB[2] + __uint_as_float(svB.y << 16), 0.f), w2B.z, p);
            p = fmaf(fmaxf(accB[3] + __uint_as_float(svB.y & 0xffff0000u), 0.f), w2B.w, p);
        }
        p += __shfl_xor(p, 16);
        p += __shfl_xor(p, 32);
        if (lane < 16)
            e_vals[c - e15 + lane] = __expf(p + b2v);

        ptc = ptn; ptn = ptn2;
#pragma unroll
        for (int g = 0; g < 8; ++g) sn[g] = sn_n[g];
        ea0 = en0; ea1 = en1; ea2 = en2; ea3 = en3; ea4 = en4;
        ea5 = en5; ea6 = en6; ea7 = en7; ea8 = en8; ea9 = en9;
    }
}

// ---------------------------------------------------------------------------
// denom: per-node run-sum of e_vals -> inv_denom; zero boundary out-rows.
// ---------------------------------------------------------------------------
__global__ __launch_bounds__(256) void denom_kernel(
    const int* __restrict__ rowptr, const float* __restrict__ e_vals,
    float* __restrict__ inv_denom, float* __restrict__ out)
{
    const int n = blockIdx.x * 256 + threadIdx.x;
    if (n >= NN) return;
    const int rs = rowptr[n], re = rowptr[n + 1];
    float s = 0.f;
    for (int c = rs; c < re; ++c) s += e_vals[c];
    inv_denom[n] = 1.f / (s + 1e-16f);
    if (re > rs && (rs >> 6) != ((re - 1) >> 6)) {
        const float4 z = make_float4(0.f, 0.f, 0.f, 0.f);
        float4* po = (float4*)&out[(size_t)n * 128];
#pragma unroll 8
        for (int q = 0; q < 32; ++q) po[q] = z;
    }
}

// ---------------------------------------------------------------------------
// vscatter: PERSISTENT grid, weights hoisted. Per 64-edge tile: inline attn
// (+ attn_out scatter, h==0 only); v via 8 MFMA (C-init = bv); LDS tile;
// rowptr-guided segment reduce; complete nodes plain-store, boundary atomics.
// ---------------------------------------------------------------------------
__global__ __launch_bounds__(256) void vscatter_kernel(
    const int* __restrict__ rowptr, const int2* __restrict__ pt,
    const unsigned int* __restrict__ eas, const float* __restrict__ e_vals,
    const float* __restrict__ inv_denom,
    const unsigned short* __restrict__ wvk_g, const float* __restrict__ bv,
    float* __restrict__ out, float* __restrict__ attn_out)
{
    __shared__ __align__(16) float w_lds[64 * 132];  // 33792 B

    const int t    = threadIdx.x;
    const int lane = t & 63;
    const int wv   = t >> 6;
    const int h    = lane >> 4;
    const int e15  = lane & 15;
    const int el   = wv * 16 + e15;

    bf16x8 av[8];
    float4 bb[8];
#pragma unroll
    for (int g = 0; g < 8; ++g) {
        av[g] = *(const bf16x8*)&wvk_g[(g * 16 + e15) * 32 + h * 8];
        bb[g] = *(const float4*)&bv[g * 16 + h * 4];
    }

    for (int tile = blockIdx.x; tile < NTILES; tile += gridDim.x) {
        const int base = tile * 64;
        const int c    = base + el;

        const int2 pc = pt[c];
        const float at = e_vals[c] * inv_denom[pc.y];
        if (h == 0) attn_out[pc.x] = at;

        bf16x8 be = (bf16x8){0, 0, 0, 0, 0, 0, 0, 0};
        {
            const unsigned int* pe = eas + (size_t)c * 5;
            if (h == 0) {
                BU bu;
                bu.u.x = pe[0]; bu.u.y = pe[1]; bu.u.z = pe[2]; bu.u.w = pe[3];
                be = bu.v;
            } else if (h == 1) {
                BU bu;
                bu.u.x = pe[4]; bu.u.y = 0; bu.u.z = 0; bu.u.w = 0;
                be = bu.v;
            }
        }

        __syncthreads();  // protect w_lds from previous tile's readers
#pragma unroll
        for (int g = 0; g < 8; ++g) {
            f32x4 cb;
            cb[0] = bb[g].x; cb[1] = bb[g].y; cb[2] = bb[g].z; cb[3] = bb[g].w;
            const f32x4 acc = __builtin_amdgcn_mfma_f32_16x16x32_bf16(av[g], be, cb, 0, 0, 0);
            float4 w;
            w.x = at * lk(acc[0]);
            w.y = at * lk(acc[1]);
            w.z = at * lk(acc[2]);
            w.w = at * lk(acc[3]);
            *(float4*)&w_lds[el * 132 + g * 16 + h * 4] = w;
        }
        __syncthreads();

        const int n_lo = (tile == 0) ? 0 : pt[base].y;
        const int n_hi = (tile == NTILES - 1) ? (NN - 1) : pt[base + 64].y;

        for (int nd = n_lo + wv; nd <= n_hi; nd += 4) {
            const int rs = rowptr[nd], re = rowptr[nd + 1];
            const int lo = max(rs, base), hi = min(re, base + 64);
            float sx = 0.f, sy = 0.f;
            for (int cc = lo; cc < hi; ++cc) {
                const float2 v = *(const float2*)&w_lds[(cc - base) * 132 + lane * 2];
                sx += v.x; sy += v.y;
            }
            float* po = &out[(size_t)nd * 128 + lane * 2];
            if (rs >= base && re <= base + 64) {
                *(float2*)po = make_float2(sx, sy);
            } else {
                atomicAdd(po, sx);
                atomicAdd(po + 1, sy);
            }
        }
    }
}

extern "C" void kernel_launch(void* const* d_in, const int* in_sizes, int n_in,
                              void* d_out, int out_size, void* d_ws, size_t ws_size,
                              hipStream_t stream)
{
    const float* x         = (const float*)d_in[0];
    const int*   eidx      = (const int*)d_in[1];
    const float* edge_attr = (const float*)d_in[2];
    const float* Wq        = (const float*)d_in[3];
    const float* Wk        = (const float*)d_in[4];
    const float* Wv        = (const float*)d_in[5];
    const float* bv        = (const float*)d_in[6];
    const float* W1        = (const float*)d_in[7];
    const float* b1        = (const float*)d_in[8];
    const float* W2        = (const float*)d_in[9];
    const float* b2        = (const float*)d_in[10];
    const int*   tgt       = eidx + NE;  // edge_index[1]

    char* ws = (char*)d_ws;
    unsigned short* w1k    = (unsigned short*)(ws + OFF_W1K);
    unsigned short* wvk    = (unsigned short*)(ws + OFF_WVK);
    unsigned short* w1bp   = (unsigned short*)(ws + OFF_W1BP);
    unsigned short* mtb    = (unsigned short*)(ws + OFF_MTB);
    int*            rowptr = (int*)(ws + OFF_RP);
    int*            cursor = (int*)(ws + OFF_CUR);
    float*          invd   = (float*)(ws + OFF_CUR);  // alias: cursor dead after fill
    int*            part   = (int*)(ws + OFF_PART);
    int*            bsum   = (int*)(ws + OFF_BSUM);
    int*            bsumx  = (int*)(ws + OFF_BSUMX);
    int*            cnt    = (int*)(ws + OFF_CNT);
    int2*           pt     = (int2*)(ws + OFF_PT);
    float*          e_vals = (float*)(ws + OFF_EVALS);
    unsigned int*   eas    = (unsigned int*)(ws + OFF_EAS);
    unsigned short* s_node = (unsigned short*)(ws + OFF_SNODE);

    float* out      = (float*)d_out;
    float* attn_out = out + (size_t)NN * 128;

    hipMemsetAsync(cnt, 0, (size_t)NN * sizeof(int), stream);

    prep_kernel<<<128, 128, 0, stream>>>(W1, Wq, Wk, Wv, w1k, wvk, w1bp, mtb);
    node_score_kernel<<<(NN + 63) / 64, 256, 0, stream>>>(x, mtb, b1, s_node);
    hist_kernel<<<(NE + 255) / 256, 256, 0, stream>>>(tgt, cnt);
    scan1_kernel<<<NB_SCAN, 256, 0, stream>>>(cnt, part, bsum);
    scan2_kernel<<<1, 512, 0, stream>>>(bsum, bsumx);
    scan3_kernel<<<NB_SCAN, 256, 0, stream>>>(part, bsumx, rowptr, cursor);
    fill_kernel<<<(NE + 255) / 256, 256, 0, stream>>>(tgt, cursor, pt);
    edge_kernel<<<1024, 256, 0, stream>>>(edge_attr, pt, w1k, w1bp, W2, b2,
                                          s_node, e_vals, eas);
    denom_kernel<<<(NN + 255) / 256, 256, 0, stream>>>(rowptr, e_vals, invd, out);
    vscatter_kernel<<<1024, 256, 0, stream>>>(rowptr, pt, eas, e_vals, invd,
                                              wvk, bv, out, attn_out);
}

// Round 13
// 296.975 us; speedup vs baseline: 1.0375x; 1.0375x over previous
//
#include <hip/hip_runtime.h>
#include <stdint.h>

#define NN 100000
#define NE 1000000
#define NTILES (NE / 64)
#define NB_SCAN 391  // ceil(NN/256)

typedef __attribute__((ext_vector_type(8))) short bf16x8;
typedef __attribute__((ext_vector_type(4))) float f32x4;

// ws layout (bytes)
static const size_t OFF_W1K   = 0;         // 128*32 bf16 (8 KB)
static const size_t OFF_WVK   = 8192;      // 128*32 bf16 (8 KB): Wv K-padded
static const size_t OFF_W1BP  = 16384;     // 128*128 bf16 (32 KB), slot-permuted
static const size_t OFF_MTB   = 49152;     // 128*128 bf16 (32 KB)
static const size_t OFF_RP    = 81920;     // (NN+1) int rowptr
static const size_t OFF_CUR   = 524288;    // NN int cursor; later aliased as inv_denom
static const size_t OFF_PART  = 1048576;   // NB_SCAN*256 int
static const size_t OFF_BSUM  = 1572864;   // NB_SCAN int
static const size_t OFF_BSUMX = 1576960;   // NB_SCAN int
static const size_t OFF_CNT   = 1581056;   // NN int histogram
static const size_t OFF_PT    = 2097152;   // NE int2 {edge, tgt} sorted (8 MB)
static const size_t OFF_EVALS = 10485760;  // NE f32 (sorted order, 4 MB)
static const size_t OFF_EAS   = 14485760;  // NE * 5 uint (bf16x10 packed, 20 MB)
static const size_t OFF_SNODE = 34485760;  // NN*128 bf16 (25.6 MB)

__device__ inline unsigned short f2bf(float f) {
    const unsigned int u = __float_as_uint(f);
    return (unsigned short)((u + 0x7fffu + ((u >> 16) & 1u)) >> 16);  // RNE
}

__device__ inline unsigned int cvtpk(float lo, float hi) {
    unsigned int r;
    asm("v_cvt_pk_bf16_f32 %0, %1, %2" : "=v"(r) : "v"(lo), "v"(hi));
    return r;
}

__device__ inline float lk2(float v) {  // leaky_relu 0.01 in 2 VALU ops
    return fmaf(0.495f, fabsf(v), 0.505f * v);
}

union BU { bf16x8 v; uint4 u; };

// ---------------------------------------------------------------------------
// prep: w1k/wvk = bf16(Wk/Wv) K-padded to 32; w1bp = W1b slot-permuted bf16;
// mtb[i][l] = bf16((W1a@Wq)[i][l]). Also zeroes cnt (replaces memset launch).
// ---------------------------------------------------------------------------
__global__ __launch_bounds__(128) void prep_kernel(
    const float* __restrict__ W1, const float* __restrict__ Wq,
    const float* __restrict__ Wk, const float* __restrict__ Wv,
    unsigned short* __restrict__ w1k, unsigned short* __restrict__ wvk,
    unsigned short* __restrict__ w1bp, unsigned short* __restrict__ mtb,
    int* __restrict__ cnt)
{
    const int l = blockIdx.x;   // 0..127
    const int i = threadIdx.x;  // 0..127
    for (int z = l * 128 + i; z < NN; z += 128 * 128) cnt[z] = 0;
    float acc = 0.f;
#pragma unroll 8
    for (int j = 0; j < 128; ++j)
        acc = fmaf(W1[i * 256 + j], Wq[j * 128 + l], acc);
    mtb[i * 128 + l] = f2bf(acc);
    if (i < 32) {
        w1k[l * 32 + i] = (i < 10) ? f2bf(Wk[l * 10 + i]) : (unsigned short)0;
        wvk[l * 32 + i] = (i < 10) ? f2bf(Wv[l * 10 + i]) : (unsigned short)0;
    }
    const int m = l;
    const int j = (m & ~31) + 16 * ((m >> 2) & 1) + 4 * ((m >> 3) & 3) + (m & 3);
    w1bp[i * 128 + m] = f2bf(W1[i * 256 + 128 + j]);
}

// ---------------------------------------------------------------------------
// node scores via MFMA: s_node[n][i] = bf16( x[n]@M^T + b1 ).  (R9-exact)
// ---------------------------------------------------------------------------
__global__ __launch_bounds__(256) void node_score_kernel(
    const float* __restrict__ x, const unsigned short* __restrict__ mtb_g,
    const float* __restrict__ b1, unsigned short* __restrict__ s_node)
{
    __shared__ __align__(16) unsigned short mt_s[128 * 136];
    const int t = threadIdx.x;
    for (int idx = t; idx < 2048; idx += 256) {
        const uint4 v = ((const uint4*)mtb_g)[idx];
        const int row = idx >> 4, q = idx & 15;
        *(uint4*)&mt_s[row * 136 + q * 8] = v;
    }
    __syncthreads();

    const int lane = t & 63;
    const int wave = t >> 6;
    const int h    = lane >> 4;
    const int e15  = lane & 15;
    const int node = blockIdx.x * 64 + wave * 16 + e15;
    const int nc   = min(node, NN - 1);
    const int lds_base = e15 * 136 + h * 8;

    const f32x4 z4 = {0.f, 0.f, 0.f, 0.f};
    f32x4 acc[8];
#pragma unroll
    for (int g = 0; g < 8; ++g) acc[g] = z4;

#pragma unroll
    for (int s = 0; s < 4; ++s) {
        const float4 xa = *(const float4*)&x[(size_t)nc * 128 + s * 32 + h * 8];
        const float4 xb = *(const float4*)&x[(size_t)nc * 128 + s * 32 + h * 8 + 4];
        BU bx;
        bx.u.x = cvtpk(xa.x, xa.y);
        bx.u.y = cvtpk(xa.z, xa.w);
        bx.u.z = cvtpk(xb.x, xb.y);
        bx.u.w = cvtpk(xb.z, xb.w);
#pragma unroll
        for (int g = 0; g < 8; ++g) {
            const bf16x8 a = *(const bf16x8*)&mt_s[lds_base + g * (16 * 136) + s * 32];
            acc[g] = __builtin_amdgcn_mfma_f32_16x16x32_bf16(a, bx.v, acc[g], 0, 0, 0);
        }
    }

    if (node < NN) {
#pragma unroll
        for (int g = 0; g < 8; ++g) {
            const float4 bb = *(const float4*)&b1[g * 16 + h * 4];
            uint2 o2;
            o2.x = cvtpk(acc[g][0] + bb.x, acc[g][1] + bb.y);
            o2.y = cvtpk(acc[g][2] + bb.z, acc[g][3] + bb.w);
            *(uint2*)&s_node[(size_t)node * 128 + g * 16 + h * 4] = o2;
        }
    }
}

// ---------------------------------------------------------------------------
// CSR build: histogram -> block scan -> fill {edge,tgt} pairs in sorted order
// ---------------------------------------------------------------------------
__global__ __launch_bounds__(256) void hist_kernel(
    const int* __restrict__ tgt, int* __restrict__ cnt)
{
    const int e = blockIdx.x * 256 + threadIdx.x;
    if (e < NE) atomicAdd(&cnt[tgt[e]], 1);
}

__global__ __launch_bounds__(256) void scan1_kernel(
    const int* __restrict__ cnt, int* __restrict__ part, int* __restrict__ bsum)
{
    __shared__ int s[256];
    const int t = threadIdx.x;
    const int idx = blockIdx.x * 256 + t;
    const int v = (idx < NN) ? cnt[idx] : 0;
    s[t] = v;
    __syncthreads();
    for (int off = 1; off < 256; off <<= 1) {
        const int u = (t >= off) ? s[t - off] : 0;
        __syncthreads();
        s[t] += u;
        __syncthreads();
    }
    part[idx] = s[t] - v;  // exclusive
    if (t == 255) bsum[blockIdx.x] = s[255];
}

__global__ __launch_bounds__(512) void scan2_kernel(
    const int* __restrict__ bsum, int* __restrict__ bsumx)
{
    __shared__ int s[512];
    const int t = threadIdx.x;
    const int v = (t < NB_SCAN) ? bsum[t] : 0;
    s[t] = v;
    __syncthreads();
    for (int off = 1; off < 512; off <<= 1) {
        const int u = (t >= off) ? s[t - off] : 0;
        __syncthreads();
        s[t] += u;
        __syncthreads();
    }
    if (t < NB_SCAN) bsumx[t] = s[t] - v;  // exclusive
}

__global__ __launch_bounds__(256) void scan3_kernel(
    const int* __restrict__ part, const int* __restrict__ bsumx,
    int* __restrict__ rowptr, int* __restrict__ cursor)
{
    const int idx = blockIdx.x * 256 + threadIdx.x;
    if (idx < NN) {
        const int rp = part[idx] + bsumx[idx >> 8];
        rowptr[idx] = rp;
        cursor[idx] = rp;
    }
    if (idx == 0) rowptr[NN] = NE;
}

__global__ __launch_bounds__(256) void fill_kernel(
    const int* __restrict__ tgt, int* __restrict__ cursor, int2* __restrict__ pt)
{
    const int e = blockIdx.x * 256 + threadIdx.x;
    if (e < NE) {
        const int tg = tgt[e];
        const int p  = atomicAdd(&cursor[tg], 1);
        pt[p] = make_int2(e, tg);
    }
}

// ---------------------------------------------------------------------------
// edge scores via MFMA, CSR-sorted, 2-deep software pipeline. R9 structure
// (grid 768, padded-136 LDS, no unroll). R13 VALU trim: s_node enters phase-2
// as the MFMA C-initializer; 2-op leaky in the pack.
// ---------------------------------------------------------------------------
__global__ __launch_bounds__(256) void edge_kernel(
    const float* __restrict__ edge_attr, const int2* __restrict__ pt,
    const unsigned short* __restrict__ w1k_g, const unsigned short* __restrict__ w1bp_g,
    const float* __restrict__ W2, const float* __restrict__ b2,
    const unsigned short* __restrict__ s_node,
    float* __restrict__ e_vals, unsigned int* __restrict__ eas)
{
    __shared__ __align__(16) unsigned short w1b_s[128 * 136];

    const int t = threadIdx.x;
    for (int idx = t; idx < 2048; idx += 256) {
        const uint4 v = ((const uint4*)w1bp_g)[idx];
        const int row = idx >> 4, q = idx & 15;
        *(uint4*)&w1b_s[row * 136 + q * 8] = v;
    }

    const int lane = t & 63;
    const int wave = t >> 6;
    const int h    = lane >> 4;
    const int e15  = lane & 15;

    bf16x8 a1[8];
#pragma unroll
    for (int f = 0; f < 8; ++f)
        a1[f] = *(const bf16x8*)&w1k_g[(f * 16 + e15) * 32 + h * 8];
    const float b2v = b2[0];

    __syncthreads();

    const int lds_base = e15 * 136 + h * 8;
    const int cstep    = gridDim.x * 64;

    int c = blockIdx.x * 64 + wave * 16 + e15;  // sorted edge index

    int2 ptc = pt[min(c, NE - 1)];
    int2 ptn = pt[min(c + cstep, NE - 1)];

    uint2 sn[8];
#pragma unroll
    for (int g = 0; g < 8; ++g)
        sn[g] = *(const uint2*)&s_node[(size_t)ptc.y * 128 + g * 16 + h * 4];

    float ea0 = 0.f, ea1 = 0.f, ea2 = 0.f, ea3 = 0.f, ea4 = 0.f;
    float ea5 = 0.f, ea6 = 0.f, ea7 = 0.f, ea8 = 0.f, ea9 = 0.f;
    {
        const float* pa = edge_attr + (size_t)ptc.x * 10;
        if (h == 0) {
            const float2 u0 = *(const float2*)(pa + 0);
            const float2 u1 = *(const float2*)(pa + 2);
            const float2 u2 = *(const float2*)(pa + 4);
            const float2 u3 = *(const float2*)(pa + 6);
            ea0 = u0.x; ea1 = u0.y; ea2 = u1.x; ea3 = u1.y;
            ea4 = u2.x; ea5 = u2.y; ea6 = u3.x; ea7 = u3.y;
        } else if (h == 1) {
            const float2 u4 = *(const float2*)(pa + 8);
            ea8 = u4.x; ea9 = u4.y;
        }
    }

    for (int tile = blockIdx.x; tile < NTILES; tile += gridDim.x, c += cstep) {
        const int2 ptn2 = pt[min(c + 2 * cstep, NE - 1)];
        uint2 sn_n[8];
#pragma unroll
        for (int g = 0; g < 8; ++g)
            sn_n[g] = *(const uint2*)&s_node[(size_t)ptn.y * 128 + g * 16 + h * 4];
        float en0 = 0.f, en1 = 0.f, en2 = 0.f, en3 = 0.f, en4 = 0.f;
        float en5 = 0.f, en6 = 0.f, en7 = 0.f, en8 = 0.f, en9 = 0.f;
        {
            const float* pa = edge_attr + (size_t)ptn.x * 10;
            if (h == 0) {
                const float2 u0 = *(const float2*)(pa + 0);
                const float2 u1 = *(const float2*)(pa + 2);
                const float2 u2 = *(const float2*)(pa + 4);
                const float2 u3 = *(const float2*)(pa + 6);
                en0 = u0.x; en1 = u0.y; en2 = u1.x; en3 = u1.y;
                en4 = u2.x; en5 = u2.y; en6 = u3.x; en7 = u3.y;
            } else if (h == 1) {
                const float2 u4 = *(const float2*)(pa + 8);
                en8 = u4.x; en9 = u4.y;
            }
        }

        bf16x8 b1 = (bf16x8){0, 0, 0, 0, 0, 0, 0, 0};
        {
            unsigned int* po = eas + (size_t)c * 5;
            if (h == 0) {
                BU bu;
                bu.u.x = cvtpk(ea0, ea1);
                bu.u.y = cvtpk(ea2, ea3);
                bu.u.z = cvtpk(ea4, ea5);
                bu.u.w = cvtpk(ea6, ea7);
                b1 = bu.v;
                po[0] = bu.u.x; po[1] = bu.u.y; po[2] = bu.u.z; po[3] = bu.u.w;
            } else if (h == 1) {
                BU bu;
                bu.u.x = cvtpk(ea8, ea9);
                bu.u.y = 0; bu.u.z = 0; bu.u.w = 0;
                b1 = bu.v;
                po[4] = bu.u.x;
            }
        }

        const f32x4 z4 = {0.f, 0.f, 0.f, 0.f};
        f32x4 acc1[8];
#pragma unroll
        for (int f = 0; f < 8; ++f)
            acc1[f] = __builtin_amdgcn_mfma_f32_16x16x32_bf16(a1[f], b1, z4, 0, 0, 0);

        bf16x8 pb[4];
#pragma unroll
        for (int s = 0; s < 4; ++s) {
            BU bu;
            bu.u.x = cvtpk(lk2(acc1[2 * s][0]), lk2(acc1[2 * s][1]));
            bu.u.y = cvtpk(lk2(acc1[2 * s][2]), lk2(acc1[2 * s][3]));
            bu.u.z = cvtpk(lk2(acc1[2 * s + 1][0]), lk2(acc1[2 * s + 1][1]));
            bu.u.w = cvtpk(lk2(acc1[2 * s + 1][2]), lk2(acc1[2 * s + 1][3]));
            pb[s] = bu.v;
        }

        float p = 0.f;
#pragma unroll
        for (int g2 = 0; g2 < 4; ++g2) {
            const int gA = 2 * g2, gB = 2 * g2 + 1;
            const uint2 svA = sn[gA], svB = sn[gB];
            f32x4 accA, accB;
            accA[0] = __uint_as_float(svA.x << 16);
            accA[1] = __uint_as_float(svA.x & 0xffff0000u);
            accA[2] = __uint_as_float(svA.y << 16);
            accA[3] = __uint_as_float(svA.y & 0xffff0000u);
            accB[0] = __uint_as_float(svB.x << 16);
            accB[1] = __uint_as_float(svB.x & 0xffff0000u);
            accB[2] = __uint_as_float(svB.y << 16);
            accB[3] = __uint_as_float(svB.y & 0xffff0000u);
#pragma unroll
            for (int s = 0; s < 4; ++s) {
                const bf16x8 a2A = *(const bf16x8*)&w1b_s[lds_base + gA * (16 * 136) + s * 32];
                const bf16x8 a2B = *(const bf16x8*)&w1b_s[lds_base + gB * (16 * 136) + s * 32];
                accA = __builtin_amdgcn_mfma_f32_16x16x32_bf16(a2A, pb[s], accA, 0, 0, 0);
                accB = __builtin_amdgcn_mfma_f32_16x16x32_bf16(a2B, pb[s], accB, 0, 0, 0);
            }
            const float4 w2A = *(const float4*)&W2[gA * 16 + h * 4];
            const float4 w2B = *(const float4*)&W2[gB * 16 + h * 4];
            p = fmaf(fmaxf(accA[0], 0.f), w2A.x, p);
            p = fmaf(fmaxf(accA[1], 0.f), w2A.y, p);
            p = fmaf(fmaxf(accA[2], 0.f), w2A.z, p);
            p = fmaf(fmaxf(accA[3], 0.f), w2A.w, p);
            p = fmaf(fmaxf(accB[0], 0.f), w2B.x, p);
            p = fmaf(fmaxf(accB[1], 0.f), w2B.y, p);
            p = fmaf(fmaxf(accB[2], 0.f), w2B.z, p);
            p = fmaf(fmaxf(accB[3], 0.f), w2B.w, p);
        }
        p += __shfl_xor(p, 16);
        p += __shfl_xor(p, 32);
        if (lane < 16)
            e_vals[c - e15 + lane] = __expf(p + b2v);

        ptc = ptn; ptn = ptn2;
#pragma unroll
        for (int g = 0; g < 8; ++g) sn[g] = sn_n[g];
        ea0 = en0; ea1 = en1; ea2 = en2; ea3 = en3; ea4 = en4;
        ea5 = en5; ea6 = en6; ea7 = en7; ea8 = en8; ea9 = en9;
    }
}

// ---------------------------------------------------------------------------
// denom: per-node run-sum of e_vals -> inv_denom; zero boundary out-rows.
// ---------------------------------------------------------------------------
__global__ __launch_bounds__(256) void denom_kernel(
    const int* __restrict__ rowptr, const float* __restrict__ e_vals,
    float* __restrict__ inv_denom, float* __restrict__ out)
{
    const int n = blockIdx.x * 256 + threadIdx.x;
    if (n >= NN) return;
    const int rs = rowptr[n], re = rowptr[n + 1];
    float s = 0.f;
    for (int c = rs; c < re; ++c) s += e_vals[c];
    inv_denom[n] = 1.f / (s + 1e-16f);
    if (re > rs && (rs >> 6) != ((re - 1) >> 6)) {
        const float4 z = make_float4(0.f, 0.f, 0.f, 0.f);
        float4* po = (float4*)&out[(size_t)n * 128];
#pragma unroll 8
        for (int q = 0; q < 32; ++q) po[q] = z;
    }
}

// ---------------------------------------------------------------------------
// vscatter: PERSISTENT grid, weights hoisted. Per 64-edge tile: inline attn
// (+ attn_out scatter, h==0 only); v via 8 MFMA (C-init = bv); LDS tile;
// rowptr-guided segment reduce; complete nodes plain-store, boundary atomics.
// ---------------------------------------------------------------------------
__global__ __launch_bounds__(256) void vscatter_kernel(
    const int* __restrict__ rowptr, const int2* __restrict__ pt,
    const unsigned int* __restrict__ eas, const float* __restrict__ e_vals,
    const float* __restrict__ inv_denom,
    const unsigned short* __restrict__ wvk_g, const float* __restrict__ bv,
    float* __restrict__ out, float* __restrict__ attn_out)
{
    __shared__ __align__(16) float w_lds[64 * 132];  // 33792 B

    const int t    = threadIdx.x;
    const int lane = t & 63;
    const int wv   = t >> 6;
    const int h    = lane >> 4;
    const int e15  = lane & 15;
    const int el   = wv * 16 + e15;

    bf16x8 av[8];
    float4 bb[8];
#pragma unroll
    for (int g = 0; g < 8; ++g) {
        av[g] = *(const bf16x8*)&wvk_g[(g * 16 + e15) * 32 + h * 8];
        bb[g] = *(const float4*)&bv[g * 16 + h * 4];
    }

    for (int tile = blockIdx.x; tile < NTILES; tile += gridDim.x) {
        const int base = tile * 64;
        const int c    = base + el;

        const int2 pc = pt[c];
        const float at = e_vals[c] * inv_denom[pc.y];
        if (h == 0) attn_out[pc.x] = at;

        bf16x8 be = (bf16x8){0, 0, 0, 0, 0, 0, 0, 0};
        {
            const unsigned int* pe = eas + (size_t)c * 5;
            if (h == 0) {
                BU bu;
                bu.u.x = pe[0]; bu.u.y = pe[1]; bu.u.z = pe[2]; bu.u.w = pe[3];
                be = bu.v;
            } else if (h == 1) {
                BU bu;
                bu.u.x = pe[4]; bu.u.y = 0; bu.u.z = 0; bu.u.w = 0;
                be = bu.v;
            }
        }

        __syncthreads();  // protect w_lds from previous tile's readers
#pragma unroll
        for (int g = 0; g < 8; ++g) {
            f32x4 cb;
            cb[0] = bb[g].x; cb[1] = bb[g].y; cb[2] = bb[g].z; cb[3] = bb[g].w;
            const f32x4 acc = __builtin_amdgcn_mfma_f32_16x16x32_bf16(av[g], be, cb, 0, 0, 0);
            float4 w;
            w.x = at * lk2(acc[0]);
            w.y = at * lk2(acc[1]);
            w.z = at * lk2(acc[2]);
            w.w = at * lk2(acc[3]);
            *(float4*)&w_lds[el * 132 + g * 16 + h * 4] = w;
        }
        __syncthreads();

        const int n_lo = (tile == 0) ? 0 : pt[base].y;
        const int n_hi = (tile == NTILES - 1) ? (NN - 1) : pt[base + 64].y;

        for (int nd = n_lo + wv; nd <= n_hi; nd += 4) {
            const int rs = rowptr[nd], re = rowptr[nd + 1];
            const int lo = max(rs, base), hi = min(re, base + 64);
            float sx = 0.f, sy = 0.f;
            for (int cc = lo; cc < hi; ++cc) {
                const float2 v = *(const float2*)&w_lds[(cc - base) * 132 + lane * 2];
                sx += v.x; sy += v.y;
            }
            float* po = &out[(size_t)nd * 128 + lane * 2];
            if (rs >= base && re <= base + 64) {
                *(float2*)po = make_float2(sx, sy);
            } else {
                atomicAdd(po, sx);
                atomicAdd(po + 1, sy);
            }
        }
    }
}

extern "C" void kernel_launch(void* const* d_in, const int* in_sizes, int n_in,
                              void* d_out, int out_size, void* d_ws, size_t ws_size,
                              hipStream_t stream)
{
    const float* x         = (const float*)d_in[0];
    const int*   eidx      = (const int*)d_in[1];
    const float* edge_attr = (const float*)d_in[2];
    const float* Wq        = (const float*)d_in[3];
    const float* Wk        = (const float*)d_in[4];
    const float* Wv        = (const float*)d_in[5];
    const float* bv        = (const float*)d_in[6];
    const float* W1        = (const float*)d_in[7];
    const float* b1        = (const float*)d_in[8];
    const float* W2        = (const float*)d_in[9];
    const float* b2        = (const float*)d_in[10];
    const int*   tgt       = eidx + NE;  // edge_index[1]

    char* ws = (char*)d_ws;
    unsigned short* w1k    = (unsigned short*)(ws + OFF_W1K);
    unsigned short* wvk    = (unsigned short*)(ws + OFF_WVK);
    unsigned short* w1bp   = (unsigned short*)(ws + OFF_W1BP);
    unsigned short* mtb    = (unsigned short*)(ws + OFF_MTB);
    int*            rowptr = (int*)(ws + OFF_RP);
    int*            cursor = (int*)(ws + OFF_CUR);
    float*          invd   = (float*)(ws + OFF_CUR);  // alias: cursor dead after fill
    int*            part   = (int*)(ws + OFF_PART);
    int*            bsum   = (int*)(ws + OFF_BSUM);
    int*            bsumx  = (int*)(ws + OFF_BSUMX);
    int*            cnt    = (int*)(ws + OFF_CNT);
    int2*           pt     = (int2*)(ws + OFF_PT);
    float*          e_vals = (float*)(ws + OFF_EVALS);
    unsigned int*   eas    = (unsigned int*)(ws + OFF_EAS);
    unsigned short* s_node = (unsigned short*)(ws + OFF_SNODE);

    float* out      = (float*)d_out;
    float* attn_out = out + (size_t)NN * 128;

    prep_kernel<<<128, 128, 0, stream>>>(W1, Wq, Wk, Wv, w1k, wvk, w1bp, mtb, cnt);
    node_score_kernel<<<(NN + 63) / 64, 256, 0, stream>>>(x, mtb, b1, s_node);
    hist_kernel<<<(NE + 255) / 256, 256, 0, stream>>>(tgt, cnt);
    scan1_kernel<<<NB_SCAN, 256, 0, stream>>>(cnt, part, bsum);
    scan2_kernel<<<1, 512, 0, stream>>>(bsum, bsumx);
    scan3_kernel<<<NB_SCAN, 256, 0, stream>>>(part, bsumx, rowptr, cursor);
    fill_kernel<<<(NE + 255) / 256, 256, 0, stream>>>(tgt, cursor, pt);
    edge_kernel<<<768, 256, 0, stream>>>(edge_attr, pt, w1k, w1bp, W2, b2,
                                         s_node, e_vals, eas);
    denom_kernel<<<(NN + 255) / 256, 256, 0, stream>>>(rowptr, e_vals, invd, out);
    vscatter_kernel<<<1024, 256, 0, stream>>>(rowptr, pt, eas, e_vals, invd,
                                              wvk, bv, out, attn_out);
}

// Round 14
// 293.237 us; speedup vs baseline: 1.0507x; 1.0127x over previous
//
#include <hip/hip_runtime.h>
#include <stdint.h>

#define NN 100000
#define NE 1000000
#define NT2 7813            // ceil(NE/128) edge tiles
#define NTILES (NE / 64)    // vscatter tiles
#define NB_SCAN 391         // ceil(NN/256)

typedef __attribute__((ext_vector_type(8))) short bf16x8;
typedef __attribute__((ext_vector_type(4))) float f32x4;
typedef __attribute__((ext_vector_type(16))) float f32x16;

// ws layout (bytes)
static const size_t OFF_W1K   = 0;         // 128*16 bf16 (4 KB): Wk K-padded to 16
static const size_t OFF_WVK   = 8192;      // 128*32 bf16 (8 KB): Wv K-padded to 32
static const size_t OFF_W1BP  = 16384;     // 128*128 bf16 (32 KB), slot-permuted (32x32 map)
static const size_t OFF_MTB   = 49152;     // 128*128 bf16 (32 KB)
static const size_t OFF_RP    = 81920;     // (NN+1) int rowptr
static const size_t OFF_CUR   = 524288;    // NN int cursor; later aliased as inv_denom
static const size_t OFF_PART  = 1048576;   // NB_SCAN*256 int
static const size_t OFF_BSUM  = 1572864;   // NB_SCAN int
static const size_t OFF_BSUMX = 1576960;   // NB_SCAN int
static const size_t OFF_CNT   = 1581056;   // NN int histogram
static const size_t OFF_PT    = 2097152;   // NE int2 {edge, tgt} sorted (8 MB)
static const size_t OFF_EVALS = 10485760;  // NE f32 (sorted order, 4 MB)
static const size_t OFF_EAS   = 14485760;  // NE * 5 uint (bf16x10 packed, 20 MB)
static const size_t OFF_SNODE = 34485760;  // NN*128 bf16 (25.6 MB)

__device__ inline unsigned short f2bf(float f) {
    const unsigned int u = __float_as_uint(f);
    return (unsigned short)((u + 0x7fffu + ((u >> 16) & 1u)) >> 16);  // RNE
}

__device__ inline unsigned int cvtpk(float lo, float hi) {
    unsigned int r;
    asm("v_cvt_pk_bf16_f32 %0, %1, %2" : "=v"(r) : "v"(lo), "v"(hi));
    return r;
}

__device__ inline float lk2(float v) {  // leaky_relu 0.01 in 2 VALU ops
    return fmaf(0.495f, fabsf(v), 0.505f * v);
}

union BU { bf16x8 v; uint4 u; };

// ---------------------------------------------------------------------------
// prep (blocks 0-127): w1k = bf16(Wk) K-padded to 16; wvk = bf16(Wv) K-padded
// to 32; w1bp = W1b columns permuted for the 32x32 slot map; mtb = (W1a@Wq).
// prep (blocks >=128): edge histogram (cnt pre-zeroed by memsetAsync).
// Slot map: sigma -> j_nat = 32*(s>>1) + 8*((s&1)+2*(jj>>2)) + (jj&3) + 4*h5
// with s=sigma>>4, h5=(sigma>>3)&1, jj=sigma&7.
// ---------------------------------------------------------------------------
__global__ __launch_bounds__(128) void prep_kernel(
    const float* __restrict__ W1, const float* __restrict__ Wq,
    const float* __restrict__ Wk, const float* __restrict__ Wv,
    unsigned short* __restrict__ w1k, unsigned short* __restrict__ wvk,
    unsigned short* __restrict__ w1bp, unsigned short* __restrict__ mtb,
    const int* __restrict__ tgt, int* __restrict__ cnt)
{
    if (blockIdx.x >= 128) {  // histogram part
        for (int e = (blockIdx.x - 128) * 128 + threadIdx.x; e < NE; e += 384 * 128)
            atomicAdd(&cnt[tgt[e]], 1);
        return;
    }
    const int l = blockIdx.x;   // 0..127
    const int i = threadIdx.x;  // 0..127
    float acc = 0.f;
#pragma unroll 8
    for (int j = 0; j < 128; ++j)
        acc = fmaf(W1[i * 256 + j], Wq[j * 128 + l], acc);
    mtb[i * 128 + l] = f2bf(acc);
    if (i < 16)
        w1k[l * 16 + i] = (i < 10) ? f2bf(Wk[l * 10 + i]) : (unsigned short)0;
    if (i < 32)
        wvk[l * 32 + i] = (i < 10) ? f2bf(Wv[l * 10 + i]) : (unsigned short)0;
    const int m = l;  // slot sigma
    const int s  = m >> 4;
    const int h5 = (m >> 3) & 1;
    const int jj = m & 7;
    const int jn = 32 * (s >> 1) + 8 * ((s & 1) + 2 * (jj >> 2)) + (jj & 3) + 4 * h5;
    w1bp[i * 128 + m] = f2bf(W1[i * 256 + 128 + jn]);
}

// ---------------------------------------------------------------------------
// node scores via MFMA: s_node[n][i] = bf16( x[n]@M^T + b1 ).  (R13-exact)
// ---------------------------------------------------------------------------
__global__ __launch_bounds__(256) void node_score_kernel(
    const float* __restrict__ x, const unsigned short* __restrict__ mtb_g,
    const float* __restrict__ b1, unsigned short* __restrict__ s_node)
{
    __shared__ __align__(16) unsigned short mt_s[128 * 136];
    const int t = threadIdx.x;
    for (int idx = t; idx < 2048; idx += 256) {
        const uint4 v = ((const uint4*)mtb_g)[idx];
        const int row = idx >> 4, q = idx & 15;
        *(uint4*)&mt_s[row * 136 + q * 8] = v;
    }
    __syncthreads();

    const int lane = t & 63;
    const int wave = t >> 6;
    const int h    = lane >> 4;
    const int e15  = lane & 15;
    const int node = blockIdx.x * 64 + wave * 16 + e15;
    const int nc   = min(node, NN - 1);
    const int lds_base = e15 * 136 + h * 8;

    const f32x4 z4 = {0.f, 0.f, 0.f, 0.f};
    f32x4 acc[8];
#pragma unroll
    for (int g = 0; g < 8; ++g) acc[g] = z4;

#pragma unroll
    for (int s = 0; s < 4; ++s) {
        const float4 xa = *(const float4*)&x[(size_t)nc * 128 + s * 32 + h * 8];
        const float4 xb = *(const float4*)&x[(size_t)nc * 128 + s * 32 + h * 8 + 4];
        BU bx;
        bx.u.x = cvtpk(xa.x, xa.y);
        bx.u.y = cvtpk(xa.z, xa.w);
        bx.u.z = cvtpk(xb.x, xb.y);
        bx.u.w = cvtpk(xb.z, xb.w);
#pragma unroll
        for (int g = 0; g < 8; ++g) {
            const bf16x8 a = *(const bf16x8*)&mt_s[lds_base + g * (16 * 136) + s * 32];
            acc[g] = __builtin_amdgcn_mfma_f32_16x16x32_bf16(a, bx.v, acc[g], 0, 0, 0);
        }
    }

    if (node < NN) {
#pragma unroll
        for (int g = 0; g < 8; ++g) {
            const float4 bb = *(const float4*)&b1[g * 16 + h * 4];
            uint2 o2;
            o2.x = cvtpk(acc[g][0] + bb.x, acc[g][1] + bb.y);
            o2.y = cvtpk(acc[g][2] + bb.z, acc[g][3] + bb.w);
            *(uint2*)&s_node[(size_t)node * 128 + g * 16 + h * 4] = o2;
        }
    }
}

// ---------------------------------------------------------------------------
// CSR build: block scan -> fill {edge,tgt} pairs in sorted order
// ---------------------------------------------------------------------------
__global__ __launch_bounds__(256) void scan1_kernel(
    const int* __restrict__ cnt, int* __restrict__ part, int* __restrict__ bsum)
{
    __shared__ int s[256];
    const int t = threadIdx.x;
    const int idx = blockIdx.x * 256 + t;
    const int v = (idx < NN) ? cnt[idx] : 0;
    s[t] = v;
    __syncthreads();
    for (int off = 1; off < 256; off <<= 1) {
        const int u = (t >= off) ? s[t - off] : 0;
        __syncthreads();
        s[t] += u;
        __syncthreads();
    }
    part[idx] = s[t] - v;  // exclusive
    if (t == 255) bsum[blockIdx.x] = s[255];
}

__global__ __launch_bounds__(512) void scan2_kernel(
    const int* __restrict__ bsum, int* __restrict__ bsumx)
{
    __shared__ int s[512];
    const int t = threadIdx.x;
    const int v = (t < NB_SCAN) ? bsum[t] : 0;
    s[t] = v;
    __syncthreads();
    for (int off = 1; off < 512; off <<= 1) {
        const int u = (t >= off) ? s[t - off] : 0;
        __syncthreads();
        s[t] += u;
        __syncthreads();
    }
    if (t < NB_SCAN) bsumx[t] = s[t] - v;  // exclusive
}

__global__ __launch_bounds__(256) void scan3_kernel(
    const int* __restrict__ part, const int* __restrict__ bsumx,
    int* __restrict__ rowptr, int* __restrict__ cursor)
{
    const int idx = blockIdx.x * 256 + threadIdx.x;
    if (idx < NN) {
        const int rp = part[idx] + bsumx[idx >> 8];
        rowptr[idx] = rp;
        cursor[idx] = rp;
    }
    if (idx == 0) rowptr[NN] = NE;
}

__global__ __launch_bounds__(256) void fill_kernel(
    const int* __restrict__ tgt, int* __restrict__ cursor, int2* __restrict__ pt)
{
    const int e = blockIdx.x * 256 + threadIdx.x;
    if (e < NE) {
        const int tg = tgt[e];
        const int p  = atomicAdd(&cursor[tg], 1);
        pt[p] = make_int2(e, tg);
    }
}

// ---------------------------------------------------------------------------
// edge scores via 32x32x16 MFMA: wave owns 32 edges (col = lane&31), halving
// per-edge LDS bytes, MFMA count, and per-lane scalar overhead vs 16x16.
// Phase-1 D layout (j = 32f+8q+r4+4h5, reg=4q+r4) feeds phase-2 B (k =
// 16s+8h5+jj) via s=2f+(q&1), jj=4(q>>1)+r4 — W1b pre-permuted to match.
// s_node enters phase-2 as the MFMA C-initializer. 2-deep pipeline.
// ---------------------------------------------------------------------------
__global__ __launch_bounds__(256) void edge_kernel(
    const float* __restrict__ edge_attr, const int2* __restrict__ pt,
    const unsigned short* __restrict__ w1k_g, const unsigned short* __restrict__ w1bp_g,
    const float* __restrict__ W2, const float* __restrict__ b2,
    const unsigned short* __restrict__ s_node,
    float* __restrict__ e_vals, unsigned int* __restrict__ eas)
{
    __shared__ __align__(16) unsigned short w1b_s[128 * 136];

    const int t = threadIdx.x;
    for (int idx = t; idx < 2048; idx += 256) {
        const uint4 v = ((const uint4*)w1bp_g)[idx];
        const int row = idx >> 4, q = idx & 15;
        *(uint4*)&w1b_s[row * 136 + q * 8] = v;
    }

    const int lane = t & 63;
    const int wave = t >> 6;
    const int h5   = lane >> 5;   // half-wave (k-group)
    const int e31  = lane & 31;   // edge within wave-tile

    // A1 frags: Wk rows, K padded to 16: a1[f] = Wk[32f+e31][8*h5 .. +8]
    bf16x8 a1[4];
#pragma unroll
    for (int f = 0; f < 4; ++f)
        a1[f] = *(const bf16x8*)&w1k_g[(f * 32 + e31) * 16 + h5 * 8];
    const float b2v = b2[0];

    __syncthreads();

    const int cstep = gridDim.x * 128;
    int c = blockIdx.x * 128 + wave * 32 + e31;  // sorted edge index

    int2 ptc = pt[min(c, NE - 1)];
    int2 ptn = pt[min(c + cstep, NE - 1)];

    // s_node C-init words: sn[4g+u] = s_node[tg][32g + 8u + 4h5 .. +4]
    uint2 sn[16];
#pragma unroll
    for (int q = 0; q < 16; ++q)
        sn[q] = *(const uint2*)&s_node[(size_t)ptc.y * 128 + (q >> 2) * 32 + (q & 3) * 8 + h5 * 4];

    float ea0 = 0.f, ea1 = 0.f, ea2 = 0.f, ea3 = 0.f, ea4 = 0.f;
    float ea5 = 0.f, ea6 = 0.f, ea7 = 0.f, ea8 = 0.f, ea9 = 0.f;
    {
        const float* pa = edge_attr + (size_t)ptc.x * 10;
        if (h5 == 0) {
            const float2 u0 = *(const float2*)(pa + 0);
            const float2 u1 = *(const float2*)(pa + 2);
            const float2 u2 = *(const float2*)(pa + 4);
            const float2 u3 = *(const float2*)(pa + 6);
            ea0 = u0.x; ea1 = u0.y; ea2 = u1.x; ea3 = u1.y;
            ea4 = u2.x; ea5 = u2.y; ea6 = u3.x; ea7 = u3.y;
        } else {
            const float2 u4 = *(const float2*)(pa + 8);
            ea8 = u4.x; ea9 = u4.y;
        }
    }

    for (int tile = blockIdx.x; tile < NT2; tile += gridDim.x, c += cstep) {
        // ---- next-tile prefetches ----
        const int2 ptn2 = pt[min(c + 2 * cstep, NE - 1)];
        uint2 sn_n[16];
#pragma unroll
        for (int q = 0; q < 16; ++q)
            sn_n[q] = *(const uint2*)&s_node[(size_t)ptn.y * 128 + (q >> 2) * 32 + (q & 3) * 8 + h5 * 4];
        float en0 = 0.f, en1 = 0.f, en2 = 0.f, en3 = 0.f, en4 = 0.f;
        float en5 = 0.f, en6 = 0.f, en7 = 0.f, en8 = 0.f, en9 = 0.f;
        {
            const float* pa = edge_attr + (size_t)ptn.x * 10;
            if (h5 == 0) {
                const float2 u0 = *(const float2*)(pa + 0);
                const float2 u1 = *(const float2*)(pa + 2);
                const float2 u2 = *(const float2*)(pa + 4);
                const float2 u3 = *(const float2*)(pa + 6);
                en0 = u0.x; en1 = u0.y; en2 = u1.x; en3 = u1.y;
                en4 = u2.x; en5 = u2.y; en6 = u3.x; en7 = u3.y;
            } else {
                const float2 u4 = *(const float2*)(pa + 8);
                en8 = u4.x; en9 = u4.y;
            }
        }

        // ---- B1 pack + eas store (guarded) ----
        bf16x8 b1 = (bf16x8){0, 0, 0, 0, 0, 0, 0, 0};
        {
            unsigned int* po = eas + (size_t)c * 5;
            if (h5 == 0) {
                BU bu;
                bu.u.x = cvtpk(ea0, ea1);
                bu.u.y = cvtpk(ea2, ea3);
                bu.u.z = cvtpk(ea4, ea5);
                bu.u.w = cvtpk(ea6, ea7);
                b1 = bu.v;
                if (c < NE) { po[0] = bu.u.x; po[1] = bu.u.y; po[2] = bu.u.z; po[3] = bu.u.w; }
            } else {
                BU bu;
                bu.u.x = cvtpk(ea8, ea9);
                bu.u.y = 0; bu.u.z = 0; bu.u.w = 0;
                b1 = bu.v;
                if (c < NE) po[4] = bu.u.x;
            }
        }

        // ---- phase 1 (4 MFMA) interleaved with pack: acc1[f] -> pb[2f],pb[2f+1]
        f32x16 z16;
#pragma unroll
        for (int q = 0; q < 16; ++q) z16[q] = 0.f;
        bf16x8 pb[8];
#pragma unroll
        for (int f = 0; f < 4; ++f) {
            const f32x16 a1r = __builtin_amdgcn_mfma_f32_32x32x16_bf16(a1[f], b1, z16, 0, 0, 0);
#pragma unroll
            for (int rho = 0; rho < 2; ++rho) {
                BU bu;
                bu.u.x = cvtpk(lk2(a1r[4 * rho + 0]), lk2(a1r[4 * rho + 1]));
                bu.u.y = cvtpk(lk2(a1r[4 * rho + 2]), lk2(a1r[4 * rho + 3]));
                bu.u.z = cvtpk(lk2(a1r[4 * rho + 8]), lk2(a1r[4 * rho + 9]));
                bu.u.w = cvtpk(lk2(a1r[4 * rho + 10]), lk2(a1r[4 * rho + 11]));
                pb[2 * f + rho] = bu.v;
            }
        }

        // ---- phase 2: 4 i-blocks x 8 K-steps, C-init = s_node, folded epilogue
        float p = 0.f;
#pragma unroll
        for (int g = 0; g < 4; ++g) {
            f32x16 acc2;
#pragma unroll
            for (int u = 0; u < 4; ++u) {
                const uint2 sv = sn[g * 4 + u];
                acc2[4 * u + 0] = __uint_as_float(sv.x << 16);
                acc2[4 * u + 1] = __uint_as_float(sv.x & 0xffff0000u);
                acc2[4 * u + 2] = __uint_as_float(sv.y << 16);
                acc2[4 * u + 3] = __uint_as_float(sv.y & 0xffff0000u);
            }
#pragma unroll
            for (int s = 0; s < 8; ++s) {
                const bf16x8 a2 = *(const bf16x8*)&w1b_s[(g * 32 + e31) * 136 + s * 16 + h5 * 8];
                acc2 = __builtin_amdgcn_mfma_f32_32x32x16_bf16(a2, pb[s], acc2, 0, 0, 0);
            }
#pragma unroll
            for (int u = 0; u < 4; ++u) {
                const float4 w2v = *(const float4*)&W2[g * 32 + u * 8 + h5 * 4];
                p = fmaf(fmaxf(acc2[4 * u + 0], 0.f), w2v.x, p);
                p = fmaf(fmaxf(acc2[4 * u + 1], 0.f), w2v.y, p);
                p = fmaf(fmaxf(acc2[4 * u + 2], 0.f), w2v.z, p);
                p = fmaf(fmaxf(acc2[4 * u + 3], 0.f), w2v.w, p);
            }
        }
        p += __shfl_xor(p, 32);
        if (lane < 32 && c < NE)
            e_vals[c] = __expf(p + b2v);  // sorted index, coalesced

        // ---- rotate pipeline ----
        ptc = ptn; ptn = ptn2;
#pragma unroll
        for (int q = 0; q < 16; ++q) sn[q] = sn_n[q];
        ea0 = en0; ea1 = en1; ea2 = en2; ea3 = en3; ea4 = en4;
        ea5 = en5; ea6 = en6; ea7 = en7; ea8 = en8; ea9 = en9;
    }
}

// ---------------------------------------------------------------------------
// denom: per-node run-sum of e_vals -> inv_denom; zero boundary out-rows.
// ---------------------------------------------------------------------------
__global__ __launch_bounds__(256) void denom_kernel(
    const int* __restrict__ rowptr, const float* __restrict__ e_vals,
    float* __restrict__ inv_denom, float* __restrict__ out)
{
    const int n = blockIdx.x * 256 + threadIdx.x;
    if (n >= NN) return;
    const int rs = rowptr[n], re = rowptr[n + 1];
    float s = 0.f;
    for (int c = rs; c < re; ++c) s += e_vals[c];
    inv_denom[n] = 1.f / (s + 1e-16f);
    if (re > rs && (rs >> 6) != ((re - 1) >> 6)) {
        const float4 z = make_float4(0.f, 0.f, 0.f, 0.f);
        float4* po = (float4*)&out[(size_t)n * 128];
#pragma unroll 8
        for (int q = 0; q < 32; ++q) po[q] = z;
    }
}

// ---------------------------------------------------------------------------
// vscatter: PERSISTENT grid, weights hoisted. (R13-exact)
// ---------------------------------------------------------------------------
__global__ __launch_bounds__(256) void vscatter_kernel(
    const int* __restrict__ rowptr, const int2* __restrict__ pt,
    const unsigned int* __restrict__ eas, const float* __restrict__ e_vals,
    const float* __restrict__ inv_denom,
    const unsigned short* __restrict__ wvk_g, const float* __restrict__ bv,
    float* __restrict__ out, float* __restrict__ attn_out)
{
    __shared__ __align__(16) float w_lds[64 * 132];  // 33792 B

    const int t    = threadIdx.x;
    const int lane = t & 63;
    const int wv   = t >> 6;
    const int h    = lane >> 4;
    const int e15  = lane & 15;
    const int el   = wv * 16 + e15;

    bf16x8 av[8];
    float4 bb[8];
#pragma unroll
    for (int g = 0; g < 8; ++g) {
        av[g] = *(const bf16x8*)&wvk_g[(g * 16 + e15) * 32 + h * 8];
        bb[g] = *(const float4*)&bv[g * 16 + h * 4];
    }

    for (int tile = blockIdx.x; tile < NTILES; tile += gridDim.x) {
        const int base = tile * 64;
        const int c    = base + el;

        const int2 pc = pt[c];
        const float at = e_vals[c] * inv_denom[pc.y];
        if (h == 0) attn_out[pc.x] = at;

        bf16x8 be = (bf16x8){0, 0, 0, 0, 0, 0, 0, 0};
        {
            const unsigned int* pe = eas + (size_t)c * 5;
            if (h == 0) {
                BU bu;
                bu.u.x = pe[0]; bu.u.y = pe[1]; bu.u.z = pe[2]; bu.u.w = pe[3];
                be = bu.v;
            } else if (h == 1) {
                BU bu;
                bu.u.x = pe[4]; bu.u.y = 0; bu.u.z = 0; bu.u.w = 0;
                be = bu.v;
            }
        }

        __syncthreads();  // protect w_lds from previous tile's readers
#pragma unroll
        for (int g = 0; g < 8; ++g) {
            f32x4 cb;
            cb[0] = bb[g].x; cb[1] = bb[g].y; cb[2] = bb[g].z; cb[3] = bb[g].w;
            const f32x4 acc = __builtin_amdgcn_mfma_f32_16x16x32_bf16(av[g], be, cb, 0, 0, 0);
            float4 w;
            w.x = at * lk2(acc[0]);
            w.y = at * lk2(acc[1]);
            w.z = at * lk2(acc[2]);
            w.w = at * lk2(acc[3]);
            *(float4*)&w_lds[el * 132 + g * 16 + h * 4] = w;
        }
        __syncthreads();

        const int n_lo = (tile == 0) ? 0 : pt[base].y;
        const int n_hi = (tile == NTILES - 1) ? (NN - 1) : pt[base + 64].y;

        for (int nd = n_lo + wv; nd <= n_hi; nd += 4) {
            const int rs = rowptr[nd], re = rowptr[nd + 1];
            const int lo = max(rs, base), hi = min(re, base + 64);
            float sx = 0.f, sy = 0.f;
            for (int cc = lo; cc < hi; ++cc) {
                const float2 v = *(const float2*)&w_lds[(cc - base) * 132 + lane * 2];
                sx += v.x; sy += v.y;
            }
            float* po = &out[(size_t)nd * 128 + lane * 2];
            if (rs >= base && re <= base + 64) {
                *(float2*)po = make_float2(sx, sy);
            } else {
                atomicAdd(po, sx);
                atomicAdd(po + 1, sy);
            }
        }
    }
}

extern "C" void kernel_launch(void* const* d_in, const int* in_sizes, int n_in,
                              void* d_out, int out_size, void* d_ws, size_t ws_size,
                              hipStream_t stream)
{
    const float* x         = (const float*)d_in[0];
    const int*   eidx      = (const int*)d_in[1];
    const float* edge_attr = (const float*)d_in[2];
    const float* Wq        = (const float*)d_in[3];
    const float* Wk        = (const float*)d_in[4];
    const float* Wv        = (const float*)d_in[5];
    const float* bv        = (const float*)d_in[6];
    const float* W1        = (const float*)d_in[7];
    const float* b1        = (const float*)d_in[8];
    const float* W2        = (const float*)d_in[9];
    const float* b2        = (const float*)d_in[10];
    const int*   tgt       = eidx + NE;  // edge_index[1]

    char* ws = (char*)d_ws;
    unsigned short* w1k    = (unsigned short*)(ws + OFF_W1K);
    unsigned short* wvk    = (unsigned short*)(ws + OFF_WVK);
    unsigned short* w1bp   = (unsigned short*)(ws + OFF_W1BP);
    unsigned short* mtb    = (unsigned short*)(ws + OFF_MTB);
    int*            rowptr = (int*)(ws + OFF_RP);
    int*            cursor = (int*)(ws + OFF_CUR);
    float*          invd   = (float*)(ws + OFF_CUR);  // alias: cursor dead after fill
    int*            part   = (int*)(ws + OFF_PART);
    int*            bsum   = (int*)(ws + OFF_BSUM);
    int*            bsumx  = (int*)(ws + OFF_BSUMX);
    int*            cnt    = (int*)(ws + OFF_CNT);
    int2*           pt     = (int2*)(ws + OFF_PT);
    float*          e_vals = (float*)(ws + OFF_EVALS);
    unsigned int*   eas    = (unsigned int*)(ws + OFF_EAS);
    unsigned short* s_node = (unsigned short*)(ws + OFF_SNODE);

    float* out      = (float*)d_out;
    float* attn_out = out + (size_t)NN * 128;

    hipMemsetAsync(cnt, 0, (size_t)NN * sizeof(int), stream);

    prep_kernel<<<512, 128, 0, stream>>>(W1, Wq, Wk, Wv, w1k, wvk, w1bp, mtb,
                                         tgt, cnt);
    node_score_kernel<<<(NN + 63) / 64, 256, 0, stream>>>(x, mtb, b1, s_node);
    scan1_kernel<<<NB_SCAN, 256, 0, stream>>>(cnt, part, bsum);
    scan2_kernel<<<1, 512, 0, stream>>>(bsum, bsumx);
    scan3_kernel<<<NB_SCAN, 256, 0, stream>>>(part, bsumx, rowptr, cursor);
    fill_kernel<<<(NE + 255) / 256, 256, 0, stream>>>(tgt, cursor, pt);
    edge_kernel<<<768, 256, 0, stream>>>(edge_attr, pt, w1k, w1bp, W2, b2,
                                         s_node, e_vals, eas);
    denom_kernel<<<(NN + 255) / 256, 256, 0, stream>>>(rowptr, e_vals, invd, out);
    vscatter_kernel<<<1024, 256, 0, stream>>>(rowptr, pt, eas, e_vals, invd,
                                              wvk, bv, out, attn_out);
}